// Round 5
// baseline (4171.707 us; speedup 1.0000x reference)
//
#include <hip/hip_runtime.h>

// fp32 pipeline with conv accumulation in (ky,kx,cin) order — matching XLA's
// internal NHWC canonicalization of NCHW convs (shared by the np reference and
// the jax 'expected'; see round-4 analysis: the np ref is fp32 and the test
// threshold only admits implementations whose fp32 accumulation order
// correlates with it; exact fp64 scores 5.0 > 1.85).
//
//   x0(4,16,116,116) -> 7 embedding convs -> (4,128,102,102)
//   sppmax -> (128,102,102) -> pf convs -> pfeat (64,96,96)
//   MLP over 921600 taps -> wts -> weighted radiance -> (3,96,96)

#define HW2 13456   // 116*116
#define NF  12
#define NGF 4

__device__ __forceinline__ float lrelu_f(float x) { return x > 0.f ? x : 0.01f * x; }

// ---------------- build x0: (4,16,116,116) = concat(gf bcast, features) ------------
__global__ __launch_bounds__(256) void k_buildx0(const float* __restrict__ features,
                                                 const float* __restrict__ gf,
                                                 float* __restrict__ out) {
    int i = blockIdx.x * 256 + threadIdx.x;
    const int total = 4 * 16 * HW2;
    if (i >= total) return;
    int n  = i / (16 * HW2);
    int r  = i - n * (16 * HW2);
    int c  = r / HW2;
    int yx = r - c * HW2;
    float v = (c < NGF) ? gf[c] : features[(n * NF + (c - NGF)) * HW2 + yx];
    out[i] = v;
}

// ---------------- implicit-GEMM 3x3 VALID conv, fp32, K-order (ky,kx,cin) ----------
// C[m][p] = sum_k W[m][k]*Im[k][p];  k = (ky*3+kx)*Cin + cin  (Cin power of 2)
// BM=64, BN=64, BK=16; 256 threads, 4x4 outputs/thread. Strictly ascending-k
// fp32 FMA accumulation per output element.
__global__ __launch_bounds__(256) void k_conv3x3(const float* __restrict__ in,
                                                 const float* __restrict__ wgt,
                                                 const float* __restrict__ bias,
                                                 float* __restrict__ out,
                                                 int N, int Cin, int H, int W,
                                                 int Cout, int relu, int cshift) {
    const int OH = H - 2, OW = W - 2;
    const int OHOW = OH * OW;
    const int Np = N * OHOW;
    const int K = Cin * 9;
    const int cmask = Cin - 1;

    __shared__ float Ws[16][64];  // [k][m]
    __shared__ float Is[16][64];  // [k][p]

    const int t  = threadIdx.x;
    const int sm = t & 63;          // staging: m or p local
    const int sk = (t >> 6) << 2;   // staging: k base (0,4,8,12)
    const int tx = t & 15;          // compute: p dim
    const int ty = t >> 4;          // compute: m dim
    const int m0 = ty * 4, n0 = tx * 4;
    const int mblk = blockIdx.y * 64, pblk = blockIdx.x * 64;

    float acc[4][4] = {};

    int  p  = pblk + sm;
    bool pv = p < Np;
    int  pp = pv ? p : 0;
    int  ni = pp / OHOW;
    int  r  = pp - ni * OHOW;
    int  oy = r / OW;
    int  ox = r - oy * OW;
    const float* inb  = in + ((size_t)ni * Cin) * H * W + (size_t)oy * W + ox;
    const float* wrow = wgt + (size_t)(mblk + sm) * K;

    for (int k0 = 0; k0 < K; k0 += 16) {
        #pragma unroll
        for (int j = 0; j < 4; ++j) {
            int kg  = k0 + sk + j;
            int kyx = kg >> cshift;        // ky*3+kx
            int cin = kg & cmask;
            int ky  = kyx / 3;
            int kx  = kyx - ky * 3;
            // W[m][k'] = w[m][cin][ky][kx] = wrow[cin*9 + kyx]
            Ws[sk + j][sm] = wrow[cin * 9 + kyx];
            float v = 0.f;
            if (pv) v = inb[((size_t)cin * H + ky) * W + kx];
            Is[sk + j][sm] = v;
        }
        __syncthreads();
        #pragma unroll
        for (int k = 0; k < 16; ++k) {
            float4 av = *(const float4*)(&Ws[k][m0]);
            float4 bv = *(const float4*)(&Is[k][n0]);
            float a[4] = {av.x, av.y, av.z, av.w};
            float b[4] = {bv.x, bv.y, bv.z, bv.w};
            #pragma unroll
            for (int i = 0; i < 4; ++i)
                #pragma unroll
                for (int j = 0; j < 4; ++j)
                    acc[i][j] += a[i] * b[j];
        }
        __syncthreads();
    }

    #pragma unroll
    for (int j = 0; j < 4; ++j) {
        int p2 = pblk + n0 + j;
        if (p2 >= Np) continue;
        int ni2 = p2 / OHOW;
        int r2  = p2 - ni2 * OHOW;
        int oy2 = r2 / OW;
        int ox2 = r2 - oy2 * OW;
        #pragma unroll
        for (int i = 0; i < 4; ++i) {
            int m = mblk + m0 + i;
            float val = acc[i][j] + bias[m];   // (dot) + bias, then lrelu
            if (relu) val = lrelu_f(val);
            out[(((size_t)ni2 * Cout + m) * OH + oy2) * OW + ox2] = val;
        }
    }
}

// ---------------- max over spp: (4,128,102,102) -> (128,102,102) ----------------
__global__ __launch_bounds__(256) void k_sppmax(const float* __restrict__ in,
                                                float* __restrict__ out) {
    int i = blockIdx.x * 256 + threadIdx.x;
    const int total = 128 * 102 * 102;  // 1331712
    if (i >= total) return;
    float m = in[i];
    #pragma unroll
    for (int s = 1; s < 4; ++s) m = fmaxf(m, in[i + s * total]);
    out[i] = m;
}

// ---------------- transpose pfeat (64,96,96) -> (9216,64) ----------------
__global__ __launch_bounds__(256) void k_transpose(const float* __restrict__ in,
                                                   float* __restrict__ out) {
    int i = blockIdx.x * 256 + threadIdx.x;
    const int total = 64 * 9216;
    if (i >= total) return;
    int o = i / 9216;
    int p = i - o * 9216;
    out[p * 64 + o] = in[i];
}

// ---------------- fused per-tap MLP -> wts (921600), fp32, reference add-order ----
__global__ __launch_bounds__(128) void k_mlp(const float* __restrict__ features,
                                             const float* __restrict__ pfeat_t,  // (9216,64)
                                             const float* __restrict__ sf_w,     // (64,12)
                                             const float* __restrict__ sf_b,
                                             const float* __restrict__ w0, const float* __restrict__ b0,
                                             const float* __restrict__ w1, const float* __restrict__ b1,
                                             const float* __restrict__ w2, const float* __restrict__ b2,
                                             float* __restrict__ wts) {
    __shared__ float vx[64][128];  // [i][thread]
    const int t   = threadIdx.x;
    const int gid = blockIdx.x * 128 + t;  // 7200*128 = 921600 exactly
    int p  = gid / 100;
    int r  = gid - p * 100;
    int s  = r / 25;
    int tp = r - s * 25;
    int dy = tp / 5;
    int dx = tp - dy * 5;
    int h  = p / 96;
    int w  = p - h * 96;

    // gather 12 tap features (crop offset 8)
    int y = 8 + h + dy, x = 8 + w + dx;
    const float* fb = features + (size_t)(s * NF) * HW2 + (size_t)y * 116 + x;
    float f[12];
    #pragma unroll
    for (int i = 0; i < 12; ++i) f[i] = fb[i * HW2];
    f[0] += (float)(dx - 2);
    f[1] += (float)(dy - 2);

    // sf = taps.sf_w + sf_b ; then v = pairf + sf  (reference order)
    const float* pft = pfeat_t + (size_t)p * 64;
    float v[64];
    #pragma unroll
    for (int o = 0; o < 64; ++o) {
        float a = 0.f;
        #pragma unroll
        for (int i = 0; i < 12; ++i) a += sf_w[o * 12 + i] * f[i];
        a += sf_b[o];
        v[o] = pft[o] + a;
    }

    // kp0: lrelu(dot + b0)
    #pragma unroll 1
    for (int o = 0; o < 64; ++o) {
        float a = 0.f;
        #pragma unroll
        for (int i = 0; i < 64; ++i) a += w0[o * 64 + i] * v[i];
        a += b0[o];
        vx[o][t] = lrelu_f(a);
    }
    #pragma unroll
    for (int i = 0; i < 64; ++i) v[i] = vx[i][t];

    // kp1: lrelu(dot + b1)
    #pragma unroll 1
    for (int o = 0; o < 64; ++o) {
        float a = 0.f;
        #pragma unroll
        for (int i = 0; i < 64; ++i) a += w1[o * 64 + i] * v[i];
        a += b1[o];
        vx[o][t] = lrelu_f(a);
    }
    #pragma unroll
    for (int i = 0; i < 64; ++i) v[i] = vx[i][t];

    // kp2: dot + b2
    float a = 0.f;
    #pragma unroll
    for (int i = 0; i < 64; ++i) a += w2[i] * v[i];
    a += b2[0];
    wts[gid] = a;
}

// ---------------- final weighted-radiance reduction -> out (3,96,96), fp32 --------
__global__ __launch_bounds__(256) void k_reduce(const float* __restrict__ wts,
                                                const float* __restrict__ radiance,
                                                float* __restrict__ out) {
    int p = blockIdx.x * 256 + threadIdx.x;  // 9216
    if (p >= 9216) return;
    int h = p / 96, w = p - h * 96;
    float sw = 0.f, un0 = 0.f, un1 = 0.f, un2 = 0.f;
    const float* wp = wts + (size_t)p * 100;
    for (int s = 0; s < 4; ++s) {
        #pragma unroll
        for (int dy = 0; dy < 5; ++dy) {
            #pragma unroll
            for (int dx = 0; dx < 5; ++dx) {
                float wv = wp[s * 25 + dy * 5 + dx];
                sw += wv;
                int y = 8 + h + dy, x = 8 + w + dx;
                const float* rb = radiance + (size_t)(s * 3) * HW2 + (size_t)y * 116 + x;
                un0 += wv * rb[0 * HW2];
                un1 += wv * rb[1 * HW2];
                un2 += wv * rb[2 * HW2];
            }
        }
    }
    float inv = 1.f / (sw + 1e-8f);
    out[0 * 9216 + p] = un0 * inv;
    out[1 * 9216 + p] = un1 * inv;
    out[2 * 9216 + p] = un2 * inv;
}

extern "C" void kernel_launch(void* const* d_in, const int* in_sizes, int n_in,
                              void* d_out, int out_size, void* d_ws, size_t ws_size,
                              hipStream_t stream) {
    const float* features = (const float*)d_in[0];
    const float* radiance = (const float*)d_in[1];
    const float* gf       = (const float*)d_in[2];
    const float* emb_w0   = (const float*)d_in[3];
    const float* emb_b0   = (const float*)d_in[4];
    const float* emb_w    = (const float*)d_in[5];
    const float* emb_b    = (const float*)d_in[6];
    const float* pf_w0    = (const float*)d_in[7];
    const float* pf_b0    = (const float*)d_in[8];
    const float* pf_w1    = (const float*)d_in[9];
    const float* pf_b1    = (const float*)d_in[10];
    const float* pf_w2    = (const float*)d_in[11];
    const float* pf_b2    = (const float*)d_in[12];
    const float* sf_w     = (const float*)d_in[13];
    const float* sf_b     = (const float*)d_in[14];
    const float* kp_w0    = (const float*)d_in[15];
    const float* kp_b0    = (const float*)d_in[16];
    const float* kp_w1    = (const float*)d_in[17];
    const float* kp_b1    = (const float*)d_in[18];
    const float* kp_w2    = (const float*)d_in[19];
    const float* kp_b2    = (const float*)d_in[20];
    float* out = (float*)d_out;

    // ping-pong fp32 buffers: 6,653,952 floats (26.6 MB) each
    float* A = (float*)d_ws;
    float* B = A + 6653952;

    k_buildx0<<<dim3((4 * 16 * HW2 + 255) / 256), 256, 0, stream>>>(features, gf, A);

    auto conv = [&](const float* in, const float* wg, const float* bi, float* o,
                    int N, int Cin, int H, int W, int Cout, int relu) {
        int OH = H - 2, OW = W - 2;
        int Np = N * OH * OW;
        int cs = (Cin == 16) ? 4 : 7;   // log2(Cin); Cin in {16,128}
        dim3 g((Np + 63) / 64, Cout / 64);
        k_conv3x3<<<g, 256, 0, stream>>>(in, wg, bi, o, N, Cin, H, W, Cout, relu, cs);
    };

    // embedding ladder
    conv(A, emb_w0,            emb_b0,        B, 4, 16,  116, 116, 128, 1);
    conv(B, emb_w + 0*147456,  emb_b + 0*128, A, 4, 128, 114, 114, 128, 1);
    conv(A, emb_w + 1*147456,  emb_b + 1*128, B, 4, 128, 112, 112, 128, 1);
    conv(B, emb_w + 2*147456,  emb_b + 2*128, A, 4, 128, 110, 110, 128, 1);
    conv(A, emb_w + 3*147456,  emb_b + 3*128, B, 4, 128, 108, 108, 128, 1);
    conv(B, emb_w + 4*147456,  emb_b + 4*128, A, 4, 128, 106, 106, 128, 1);
    conv(A, emb_w + 5*147456,  emb_b + 5*128, B, 4, 128, 104, 104, 128, 0);

    // max over spp: B (4,128,102,102) -> A (128,102,102)
    k_sppmax<<<dim3(1331712 / 256), 256, 0, stream>>>(B, A);

    // pixel-feature convs
    conv(A, pf_w0, pf_b0, B, 1, 128, 102, 102, 128, 1);
    conv(B, pf_w1, pf_b1, A, 1, 128, 100, 100, 128, 1);
    conv(A, pf_w2, pf_b2, B, 1, 128, 98,  98,  64,  0);

    // pfeat (64,96,96) in B -> pfeat_t (9216,64) in A
    k_transpose<<<dim3(589824 / 256), 256, 0, stream>>>(B, A);

    // fused MLP -> wts in B (921600 floats)
    k_mlp<<<dim3(7200), 128, 0, stream>>>(features, A, sf_w, sf_b,
                                          kp_w0, kp_b0, kp_w1, kp_b1, kp_w2, kp_b2, B);

    // weighted radiance -> out
    k_reduce<<<dim3(36), 256, 0, stream>>>(B, radiance, out);
}

// Round 6
// 3033.913 us; speedup vs baseline: 1.3750x; 1.3750x over previous
//
#include <hip/hip_runtime.h>

// PASSING numerics contract (round 5, absmax 0.00195): every conv output must
// be a strictly sequential fp32 FMA chain in (ky,kx outer, cin inner) order,
// bias added after, fp32 stores. Do NOT reorder/split K, do NOT change dtype.
//
// Round 6 change: direct-conv kernel. Full-Cin 10x10 input tile in LDS
// (51.2 KB, 3 blocks/CU), all Cout per block, weights pre-transposed to
// [kyx][cin][m] and read as wave-uniform scalar loads (m-slice per wave).
// One barrier per block; zero barriers in the K loop.

#define HW2 13456   // 116*116
#define NF  12
#define NGF 4

__device__ __forceinline__ float lrelu_f(float x) { return x > 0.f ? x : 0.01f * x; }

// ---------------- build x0: (4,16,116,116) = concat(gf bcast, features) ------------
__global__ __launch_bounds__(256) void k_buildx0(const float* __restrict__ features,
                                                 const float* __restrict__ gf,
                                                 float* __restrict__ out) {
    int i = blockIdx.x * 256 + threadIdx.x;
    const int total = 4 * 16 * HW2;
    if (i >= total) return;
    int n  = i / (16 * HW2);
    int r  = i - n * (16 * HW2);
    int c  = r / HW2;
    int yx = r - c * HW2;
    float v = (c < NGF) ? gf[c] : features[(n * NF + (c - NGF)) * HW2 + yx];
    out[i] = v;
}

// ---------------- weight transpose: W[m][cin][ky][kx] -> Wt[kyx][cin][m] -----------
__global__ __launch_bounds__(256) void k_wt(const float* __restrict__ w,
                                            float* __restrict__ wt,
                                            int Cout, int Cin) {
    int i = blockIdx.x * 256 + threadIdx.x;
    int total = Cout * Cin * 9;
    if (i >= total) return;
    int m   = i / (Cin * 9);
    int r   = i - m * (Cin * 9);
    int cin = r / 9;
    int kyx = r - cin * 9;
    wt[(kyx * Cin + cin) * Cout + m] = w[i];
}

// ---------------- direct 3x3 VALID conv, order-preserving ----------------
// Block: 256 threads = 4 waves. 8x8 output tile, all COUT channels.
// Wave wv computes m in [wv*MW, (wv+1)*MW), MW = COUT/4. Lane = output pixel.
// Weights wt[kyx][cin][m]: wave-uniform rows -> scalar loads.
template <int CIN, int COUT>
__global__ __launch_bounds__(256) void k_convd(const float* __restrict__ in,
                                               const float* __restrict__ wt,
                                               const float* __restrict__ bias,
                                               float* __restrict__ out,
                                               int H, int W, int relu) {
    constexpr int MW = COUT / 4;
    const int OH = H - 2, OW = W - 2;
    const int n   = blockIdx.z;
    const int ty0 = blockIdx.y * 8, tx0 = blockIdx.x * 8;

    __shared__ float It[CIN * 100];   // [cin][y(10)][x(10)]

    const int tid = threadIdx.x;

    // ---- stage input tile (clamped halo reads; clamped values never used) ----
    const float* inb = in + (size_t)n * CIN * H * W;
    for (int i = tid; i < CIN * 100; i += 256) {
        int cin = i / 100;
        int r   = i - cin * 100;
        int y   = r / 10;
        int x   = r - y * 10;
        int gy = ty0 + y; if (gy > H - 1) gy = H - 1;
        int gx = tx0 + x; if (gx > W - 1) gx = W - 1;
        It[i] = inb[((size_t)cin * H + gy) * W + gx];
    }
    __syncthreads();

    const int lane  = tid & 63;
    const int wv    = __builtin_amdgcn_readfirstlane(tid >> 6);
    const int ly    = lane >> 3, lx = lane & 7;
    const int lbase = ly * 10 + lx;

    float acc[MW];
    #pragma unroll
    for (int mi = 0; mi < MW; ++mi) acc[mi] = 0.f;

    // ---- K loop: ky,kx outer, cin inner (REQUIRED order), no barriers ----
    for (int ky = 0; ky < 3; ++ky) {
        for (int kx = 0; kx < 3; ++kx) {
            const int kyx  = ky * 3 + kx;
            const int aoff = lbase + ky * 10 + kx;
            const float* wrow = wt + (size_t)kyx * CIN * COUT + wv * MW;  // uniform
            #pragma unroll 8
            for (int cin = 0; cin < CIN; ++cin) {
                float v = It[cin * 100 + aoff];
                const float* wr = wrow + (size_t)cin * COUT;   // uniform -> s_load
                #pragma unroll
                for (int mi = 0; mi < MW; ++mi)
                    acc[mi] += wr[mi] * v;
            }
        }
    }

    // ---- epilogue ----
    int oy = ty0 + ly, ox = tx0 + lx;
    if (oy < OH && ox < OW) {
        #pragma unroll
        for (int mi = 0; mi < MW; ++mi) {
            int m = wv * MW + mi;
            float val = acc[mi] + bias[m];
            if (relu) val = lrelu_f(val);
            out[(((size_t)n * COUT + m) * OH + oy) * OW + ox] = val;
        }
    }
}

// ---------------- max over spp: (4,128,102,102) -> (128,102,102) ----------------
__global__ __launch_bounds__(256) void k_sppmax(const float* __restrict__ in,
                                                float* __restrict__ out) {
    int i = blockIdx.x * 256 + threadIdx.x;
    const int total = 128 * 102 * 102;  // 1331712
    if (i >= total) return;
    float m = in[i];
    #pragma unroll
    for (int s = 1; s < 4; ++s) m = fmaxf(m, in[i + s * total]);
    out[i] = m;
}

// ---------------- transpose pfeat (64,96,96) -> (9216,64) ----------------
__global__ __launch_bounds__(256) void k_transpose(const float* __restrict__ in,
                                                   float* __restrict__ out) {
    int i = blockIdx.x * 256 + threadIdx.x;
    const int total = 64 * 9216;
    if (i >= total) return;
    int o = i / 9216;
    int p = i - o * 9216;
    out[p * 64 + o] = in[i];
}

// ---------------- fused per-tap MLP -> wts (921600), fp32, reference add-order ----
__global__ __launch_bounds__(128) void k_mlp(const float* __restrict__ features,
                                             const float* __restrict__ pfeat_t,  // (9216,64)
                                             const float* __restrict__ sf_w,     // (64,12)
                                             const float* __restrict__ sf_b,
                                             const float* __restrict__ w0, const float* __restrict__ b0,
                                             const float* __restrict__ w1, const float* __restrict__ b1,
                                             const float* __restrict__ w2, const float* __restrict__ b2,
                                             float* __restrict__ wts) {
    __shared__ float vx[64][128];  // [i][thread]
    const int t   = threadIdx.x;
    const int gid = blockIdx.x * 128 + t;  // 7200*128 = 921600 exactly
    int p  = gid / 100;
    int r  = gid - p * 100;
    int s  = r / 25;
    int tp = r - s * 25;
    int dy = tp / 5;
    int dx = tp - dy * 5;
    int h  = p / 96;
    int w  = p - h * 96;

    // gather 12 tap features (crop offset 8)
    int y = 8 + h + dy, x = 8 + w + dx;
    const float* fb = features + (size_t)(s * NF) * HW2 + (size_t)y * 116 + x;
    float f[12];
    #pragma unroll
    for (int i = 0; i < 12; ++i) f[i] = fb[i * HW2];
    f[0] += (float)(dx - 2);
    f[1] += (float)(dy - 2);

    // sf = taps.sf_w + sf_b ; then v = pairf + sf  (reference order)
    const float* pft = pfeat_t + (size_t)p * 64;
    float v[64];
    #pragma unroll
    for (int o = 0; o < 64; ++o) {
        float a = 0.f;
        #pragma unroll
        for (int i = 0; i < 12; ++i) a += sf_w[o * 12 + i] * f[i];
        a += sf_b[o];
        v[o] = pft[o] + a;
    }

    // kp0: lrelu(dot + b0)
    #pragma unroll 1
    for (int o = 0; o < 64; ++o) {
        float a = 0.f;
        #pragma unroll
        for (int i = 0; i < 64; ++i) a += w0[o * 64 + i] * v[i];
        a += b0[o];
        vx[o][t] = lrelu_f(a);
    }
    #pragma unroll
    for (int i = 0; i < 64; ++i) v[i] = vx[i][t];

    // kp1: lrelu(dot + b1)
    #pragma unroll 1
    for (int o = 0; o < 64; ++o) {
        float a = 0.f;
        #pragma unroll
        for (int i = 0; i < 64; ++i) a += w1[o * 64 + i] * v[i];
        a += b1[o];
        vx[o][t] = lrelu_f(a);
    }
    #pragma unroll
    for (int i = 0; i < 64; ++i) v[i] = vx[i][t];

    // kp2: dot + b2
    float a = 0.f;
    #pragma unroll
    for (int i = 0; i < 64; ++i) a += w2[i] * v[i];
    a += b2[0];
    wts[gid] = a;
}

// ---------------- final weighted-radiance reduction -> out (3,96,96), fp32 --------
__global__ __launch_bounds__(256) void k_reduce(const float* __restrict__ wts,
                                                const float* __restrict__ radiance,
                                                float* __restrict__ out) {
    int p = blockIdx.x * 256 + threadIdx.x;  // 9216
    if (p >= 9216) return;
    int h = p / 96, w = p - h * 96;
    float sw = 0.f, un0 = 0.f, un1 = 0.f, un2 = 0.f;
    const float* wp = wts + (size_t)p * 100;
    for (int s = 0; s < 4; ++s) {
        #pragma unroll
        for (int dy = 0; dy < 5; ++dy) {
            #pragma unroll
            for (int dx = 0; dx < 5; ++dx) {
                float wv = wp[s * 25 + dy * 5 + dx];
                sw += wv;
                int y = 8 + h + dy, x = 8 + w + dx;
                const float* rb = radiance + (size_t)(s * 3) * HW2 + (size_t)y * 116 + x;
                un0 += wv * rb[0 * HW2];
                un1 += wv * rb[1 * HW2];
                un2 += wv * rb[2 * HW2];
            }
        }
    }
    float inv = 1.f / (sw + 1e-8f);
    out[0 * 9216 + p] = un0 * inv;
    out[1 * 9216 + p] = un1 * inv;
    out[2 * 9216 + p] = un2 * inv;
}

extern "C" void kernel_launch(void* const* d_in, const int* in_sizes, int n_in,
                              void* d_out, int out_size, void* d_ws, size_t ws_size,
                              hipStream_t stream) {
    const float* features = (const float*)d_in[0];
    const float* radiance = (const float*)d_in[1];
    const float* gf       = (const float*)d_in[2];
    const float* emb_w0   = (const float*)d_in[3];
    const float* emb_b0   = (const float*)d_in[4];
    const float* emb_w    = (const float*)d_in[5];
    const float* emb_b    = (const float*)d_in[6];
    const float* pf_w0    = (const float*)d_in[7];
    const float* pf_b0    = (const float*)d_in[8];
    const float* pf_w1    = (const float*)d_in[9];
    const float* pf_b1    = (const float*)d_in[10];
    const float* pf_w2    = (const float*)d_in[11];
    const float* pf_b2    = (const float*)d_in[12];
    const float* sf_w     = (const float*)d_in[13];
    const float* sf_b     = (const float*)d_in[14];
    const float* kp_w0    = (const float*)d_in[15];
    const float* kp_b0    = (const float*)d_in[16];
    const float* kp_w1    = (const float*)d_in[17];
    const float* kp_b1    = (const float*)d_in[18];
    const float* kp_w2    = (const float*)d_in[19];
    const float* kp_b2    = (const float*)d_in[20];
    float* out = (float*)d_out;

    // ---- workspace layout ----
    // WT region: transposed weights [kyx][cin][m] for 10 conv layers, 1,271,808 floats
    float* WT = (float*)d_ws;
    float* wt0  = WT;                      // conv1: 16x9x128      = 18432
    float* wtE0 = WT + 18432;              // emb i: 128x9x128     = 147456 each
    float* wtP0 = WT + 18432 + 6 * 147456; // 903168
    float* wtP1 = WT + 1050624;
    float* wtP2 = WT + 1198080;            // 64-out: 128x9x64     = 73728  (end 1271808)
    float* A = WT + 1271808;               // ping-pong fp32 buffers, 6653952 floats each
    float* B = A + 6653952;

    // ---- weight transposes (tiny) ----
    auto wtr = [&](const float* w, float* dst, int Cout, int Cin) {
        int total = Cout * Cin * 9;
        k_wt<<<dim3((total + 255) / 256), 256, 0, stream>>>(w, dst, Cout, Cin);
    };
    wtr(emb_w0, wt0, 128, 16);
    for (int i = 0; i < 6; ++i) wtr(emb_w + i * 147456, wtE0 + i * 147456, 128, 128);
    wtr(pf_w0, wtP0, 128, 128);
    wtr(pf_w1, wtP1, 128, 128);
    wtr(pf_w2, wtP2, 64, 128);

    k_buildx0<<<dim3((4 * 16 * HW2 + 255) / 256), 256, 0, stream>>>(features, gf, A);

    auto grid8 = [](int OH, int OW, int N) {
        return dim3((OW + 7) / 8, (OH + 7) / 8, N);
    };

    // embedding ladder
    k_convd<16, 128><<<grid8(114, 114, 4), 256, 0, stream>>>(A, wt0, emb_b0, B, 116, 116, 1);
    k_convd<128,128><<<grid8(112, 112, 4), 256, 0, stream>>>(B, wtE0 + 0*147456, emb_b + 0*128, A, 114, 114, 1);
    k_convd<128,128><<<grid8(110, 110, 4), 256, 0, stream>>>(A, wtE0 + 1*147456, emb_b + 1*128, B, 112, 112, 1);
    k_convd<128,128><<<grid8(108, 108, 4), 256, 0, stream>>>(B, wtE0 + 2*147456, emb_b + 2*128, A, 110, 110, 1);
    k_convd<128,128><<<grid8(106, 106, 4), 256, 0, stream>>>(A, wtE0 + 3*147456, emb_b + 3*128, B, 108, 108, 1);
    k_convd<128,128><<<grid8(104, 104, 4), 256, 0, stream>>>(B, wtE0 + 4*147456, emb_b + 4*128, A, 106, 106, 1);
    k_convd<128,128><<<grid8(102, 102, 4), 256, 0, stream>>>(A, wtE0 + 5*147456, emb_b + 5*128, B, 104, 104, 0);

    // max over spp: B (4,128,102,102) -> A (128,102,102)
    k_sppmax<<<dim3(1331712 / 256), 256, 0, stream>>>(B, A);

    // pixel-feature convs (N=1)
    k_convd<128,128><<<grid8(100, 100, 1), 256, 0, stream>>>(A, wtP0, pf_b0, B, 102, 102, 1);
    k_convd<128,128><<<grid8(98,  98,  1), 256, 0, stream>>>(B, wtP1, pf_b1, A, 100, 100, 1);
    k_convd<128, 64><<<grid8(96,  96,  1), 256, 0, stream>>>(A, wtP2, pf_b2, B, 98,  98,  0);

    // pfeat (64,96,96) in B -> pfeat_t (9216,64) in A
    k_transpose<<<dim3(589824 / 256), 256, 0, stream>>>(B, A);

    // fused MLP -> wts in B (921600 floats)
    k_mlp<<<dim3(7200), 128, 0, stream>>>(features, A, sf_w, sf_b,
                                          kp_w0, kp_b0, kp_w1, kp_b1, kp_w2, kp_b2, B);

    // weighted radiance -> out
    k_reduce<<<dim3(36), 256, 0, stream>>>(B, radiance, out);
}

// Round 7
// 2904.972 us; speedup vs baseline: 1.4361x; 1.0444x over previous
//
#include <hip/hip_runtime.h>

// PASSING numerics contract (round 5, absmax 0.00195): every conv output must
// be a strictly sequential fp32 FMA chain in (ky,kx outer, cin inner) order,
// bias added after, fp32 stores. MLP layers: per-output sequential ascending-i
// chain, +bias, lrelu. Do NOT reorder/split K, do NOT change dtype.
//
// Round 7: MLP ILP fix — outputs computed 8 at a time (8 independent chains,
// each chain order-identical to the passing version). pf_w2 conv writes the
// (9216,64) transpose directly (k_transpose removed).

#define HW2 13456   // 116*116
#define NF  12
#define NGF 4

__device__ __forceinline__ float lrelu_f(float x) { return x > 0.f ? x : 0.01f * x; }

// ---------------- build x0: (4,16,116,116) = concat(gf bcast, features) ------------
__global__ __launch_bounds__(256) void k_buildx0(const float* __restrict__ features,
                                                 const float* __restrict__ gf,
                                                 float* __restrict__ out) {
    int i = blockIdx.x * 256 + threadIdx.x;
    const int total = 4 * 16 * HW2;
    if (i >= total) return;
    int n  = i / (16 * HW2);
    int r  = i - n * (16 * HW2);
    int c  = r / HW2;
    int yx = r - c * HW2;
    float v = (c < NGF) ? gf[c] : features[(n * NF + (c - NGF)) * HW2 + yx];
    out[i] = v;
}

// ---------------- weight transpose: W[m][cin][ky][kx] -> Wt[kyx][cin][m] -----------
__global__ __launch_bounds__(256) void k_wt(const float* __restrict__ w,
                                            float* __restrict__ wt,
                                            int Cout, int Cin) {
    int i = blockIdx.x * 256 + threadIdx.x;
    int total = Cout * Cin * 9;
    if (i >= total) return;
    int m   = i / (Cin * 9);
    int r   = i - m * (Cin * 9);
    int cin = r / 9;
    int kyx = r - cin * 9;
    wt[(kyx * Cin + cin) * Cout + m] = w[i];
}

// ---------------- direct 3x3 VALID conv, order-preserving ----------------
// Block: 256 threads = 4 waves. 8x8 output tile, all COUT channels.
// Wave wv computes m in [wv*MW, (wv+1)*MW), MW = COUT/4. Lane = output pixel.
// Weights wt[kyx][cin][m]: wave-uniform rows -> scalar loads.
// tout=1: store transposed as out[(oy*OW+ox)*COUT + m] (requires N==1).
template <int CIN, int COUT>
__global__ __launch_bounds__(256) void k_convd(const float* __restrict__ in,
                                               const float* __restrict__ wt,
                                               const float* __restrict__ bias,
                                               float* __restrict__ out,
                                               int H, int W, int relu, int tout) {
    constexpr int MW = COUT / 4;
    const int OH = H - 2, OW = W - 2;
    const int n   = blockIdx.z;
    const int ty0 = blockIdx.y * 8, tx0 = blockIdx.x * 8;

    __shared__ float It[CIN * 100];   // [cin][y(10)][x(10)]

    const int tid = threadIdx.x;

    // ---- stage input tile (clamped halo reads; clamped values never used) ----
    const float* inb = in + (size_t)n * CIN * H * W;
    for (int i = tid; i < CIN * 100; i += 256) {
        int cin = i / 100;
        int r   = i - cin * 100;
        int y   = r / 10;
        int x   = r - y * 10;
        int gy = ty0 + y; if (gy > H - 1) gy = H - 1;
        int gx = tx0 + x; if (gx > W - 1) gx = W - 1;
        It[i] = inb[((size_t)cin * H + gy) * W + gx];
    }
    __syncthreads();

    const int lane  = tid & 63;
    const int wv    = __builtin_amdgcn_readfirstlane(tid >> 6);
    const int ly    = lane >> 3, lx = lane & 7;
    const int lbase = ly * 10 + lx;

    float acc[MW];
    #pragma unroll
    for (int mi = 0; mi < MW; ++mi) acc[mi] = 0.f;

    // ---- K loop: ky,kx outer, cin inner (REQUIRED order), no barriers ----
    for (int ky = 0; ky < 3; ++ky) {
        for (int kx = 0; kx < 3; ++kx) {
            const int kyx  = ky * 3 + kx;
            const int aoff = lbase + ky * 10 + kx;
            const float* wrow = wt + (size_t)kyx * CIN * COUT + wv * MW;  // uniform
            #pragma unroll 8
            for (int cin = 0; cin < CIN; ++cin) {
                float v = It[cin * 100 + aoff];
                const float* wr = wrow + (size_t)cin * COUT;   // uniform -> s_load
                #pragma unroll
                for (int mi = 0; mi < MW; ++mi)
                    acc[mi] += wr[mi] * v;
            }
        }
    }

    // ---- epilogue ----
    int oy = ty0 + ly, ox = tx0 + lx;
    if (oy < OH && ox < OW) {
        if (tout) {
            float* ob = out + (size_t)(oy * OW + ox) * COUT;
            #pragma unroll
            for (int mi = 0; mi < MW; ++mi) {
                int m = wv * MW + mi;
                float val = acc[mi] + bias[m];
                if (relu) val = lrelu_f(val);
                ob[m] = val;
            }
        } else {
            #pragma unroll
            for (int mi = 0; mi < MW; ++mi) {
                int m = wv * MW + mi;
                float val = acc[mi] + bias[m];
                if (relu) val = lrelu_f(val);
                out[(((size_t)n * COUT + m) * OH + oy) * OW + ox] = val;
            }
        }
    }
}

// ---------------- max over spp: (4,128,102,102) -> (128,102,102) ----------------
__global__ __launch_bounds__(256) void k_sppmax(const float* __restrict__ in,
                                                float* __restrict__ out) {
    int i = blockIdx.x * 256 + threadIdx.x;
    const int total = 128 * 102 * 102;  // 1331712
    if (i >= total) return;
    float m = in[i];
    #pragma unroll
    for (int s = 1; s < 4; ++s) m = fmaxf(m, in[i + s * total]);
    out[i] = m;
}

// ---------------- fused per-tap MLP -> wts (921600), fp32, reference add-order ----
// ILP fix: outputs in groups of 8 (8 independent chains; each chain remains the
// exact ascending-i sequential sum of the passing round-5 version).
__global__ __launch_bounds__(128) void k_mlp(const float* __restrict__ features,
                                             const float* __restrict__ pfeat_t,  // (9216,64)
                                             const float* __restrict__ sf_w,     // (64,12)
                                             const float* __restrict__ sf_b,
                                             const float* __restrict__ w0, const float* __restrict__ b0,
                                             const float* __restrict__ w1, const float* __restrict__ b1,
                                             const float* __restrict__ w2, const float* __restrict__ b2,
                                             float* __restrict__ wts) {
    __shared__ float vx[64][128];  // [i][thread]
    const int t   = threadIdx.x;
    const int gid = blockIdx.x * 128 + t;  // 7200*128 = 921600 exactly
    int p  = gid / 100;
    int r  = gid - p * 100;
    int s  = r / 25;
    int tp = r - s * 25;
    int dy = tp / 5;
    int dx = tp - dy * 5;
    int h  = p / 96;
    int w  = p - h * 96;

    // gather 12 tap features (crop offset 8)
    int y = 8 + h + dy, x = 8 + w + dx;
    const float* fb = features + (size_t)(s * NF) * HW2 + (size_t)y * 116 + x;
    float f[12];
    #pragma unroll
    for (int i = 0; i < 12; ++i) f[i] = fb[i * HW2];
    f[0] += (float)(dx - 2);
    f[1] += (float)(dy - 2);

    // sf = taps.sf_w + sf_b ; then v = pairf + sf  (reference order)
    const float* pft = pfeat_t + (size_t)p * 64;
    float v[64];
    #pragma unroll
    for (int o = 0; o < 64; ++o) {
        float a = 0.f;
        #pragma unroll
        for (int i = 0; i < 12; ++i) a += sf_w[o * 12 + i] * f[i];
        a += sf_b[o];
        v[o] = pft[o] + a;
    }

    // kp0: lrelu(dot + b0), 8 outputs in flight
    #pragma unroll 1
    for (int ob = 0; ob < 64; ob += 8) {
        float acc[8];
        #pragma unroll
        for (int j = 0; j < 8; ++j) acc[j] = 0.f;
        #pragma unroll
        for (int i = 0; i < 64; ++i) {
            float vi = v[i];
            #pragma unroll
            for (int j = 0; j < 8; ++j) acc[j] += w0[(ob + j) * 64 + i] * vi;
        }
        #pragma unroll
        for (int j = 0; j < 8; ++j) vx[ob + j][t] = lrelu_f(acc[j] + b0[ob + j]);
    }
    #pragma unroll
    for (int i = 0; i < 64; ++i) v[i] = vx[i][t];

    // kp1: lrelu(dot + b1), 8 outputs in flight
    #pragma unroll 1
    for (int ob = 0; ob < 64; ob += 8) {
        float acc[8];
        #pragma unroll
        for (int j = 0; j < 8; ++j) acc[j] = 0.f;
        #pragma unroll
        for (int i = 0; i < 64; ++i) {
            float vi = v[i];
            #pragma unroll
            for (int j = 0; j < 8; ++j) acc[j] += w1[(ob + j) * 64 + i] * vi;
        }
        #pragma unroll
        for (int j = 0; j < 8; ++j) vx[ob + j][t] = lrelu_f(acc[j] + b1[ob + j]);
    }
    #pragma unroll
    for (int i = 0; i < 64; ++i) v[i] = vx[i][t];

    // kp2: dot + b2
    float a = 0.f;
    #pragma unroll
    for (int i = 0; i < 64; ++i) a += w2[i] * v[i];
    a += b2[0];
    wts[gid] = a;
}

// ---------------- final weighted-radiance reduction -> out (3,96,96), fp32 --------
__global__ __launch_bounds__(256) void k_reduce(const float* __restrict__ wts,
                                                const float* __restrict__ radiance,
                                                float* __restrict__ out) {
    int p = blockIdx.x * 256 + threadIdx.x;  // 9216
    if (p >= 9216) return;
    int h = p / 96, w = p - h * 96;
    float sw = 0.f, un0 = 0.f, un1 = 0.f, un2 = 0.f;
    const float* wp = wts + (size_t)p * 100;
    for (int s = 0; s < 4; ++s) {
        #pragma unroll
        for (int dy = 0; dy < 5; ++dy) {
            #pragma unroll
            for (int dx = 0; dx < 5; ++dx) {
                float wv = wp[s * 25 + dy * 5 + dx];
                sw += wv;
                int y = 8 + h + dy, x = 8 + w + dx;
                const float* rb = radiance + (size_t)(s * 3) * HW2 + (size_t)y * 116 + x;
                un0 += wv * rb[0 * HW2];
                un1 += wv * rb[1 * HW2];
                un2 += wv * rb[2 * HW2];
            }
        }
    }
    float inv = 1.f / (sw + 1e-8f);
    out[0 * 9216 + p] = un0 * inv;
    out[1 * 9216 + p] = un1 * inv;
    out[2 * 9216 + p] = un2 * inv;
}

extern "C" void kernel_launch(void* const* d_in, const int* in_sizes, int n_in,
                              void* d_out, int out_size, void* d_ws, size_t ws_size,
                              hipStream_t stream) {
    const float* features = (const float*)d_in[0];
    const float* radiance = (const float*)d_in[1];
    const float* gf       = (const float*)d_in[2];
    const float* emb_w0   = (const float*)d_in[3];
    const float* emb_b0   = (const float*)d_in[4];
    const float* emb_w    = (const float*)d_in[5];
    const float* emb_b    = (const float*)d_in[6];
    const float* pf_w0    = (const float*)d_in[7];
    const float* pf_b0    = (const float*)d_in[8];
    const float* pf_w1    = (const float*)d_in[9];
    const float* pf_b1    = (const float*)d_in[10];
    const float* pf_w2    = (const float*)d_in[11];
    const float* pf_b2    = (const float*)d_in[12];
    const float* sf_w     = (const float*)d_in[13];
    const float* sf_b     = (const float*)d_in[14];
    const float* kp_w0    = (const float*)d_in[15];
    const float* kp_b0    = (const float*)d_in[16];
    const float* kp_w1    = (const float*)d_in[17];
    const float* kp_b1    = (const float*)d_in[18];
    const float* kp_w2    = (const float*)d_in[19];
    const float* kp_b2    = (const float*)d_in[20];
    float* out = (float*)d_out;

    // ---- workspace layout ----
    float* WT = (float*)d_ws;
    float* wt0  = WT;                      // conv1: 16x9x128      = 18432
    float* wtE0 = WT + 18432;              // emb i: 128x9x128     = 147456 each
    float* wtP0 = WT + 18432 + 6 * 147456; // 903168
    float* wtP1 = WT + 1050624;
    float* wtP2 = WT + 1198080;            // 64-out: 128x9x64     = 73728  (end 1271808)
    float* A = WT + 1271808;               // ping-pong fp32 buffers, 6653952 floats each
    float* B = A + 6653952;

    // ---- weight transposes (tiny) ----
    auto wtr = [&](const float* w, float* dst, int Cout, int Cin) {
        int total = Cout * Cin * 9;
        k_wt<<<dim3((total + 255) / 256), 256, 0, stream>>>(w, dst, Cout, Cin);
    };
    wtr(emb_w0, wt0, 128, 16);
    for (int i = 0; i < 6; ++i) wtr(emb_w + i * 147456, wtE0 + i * 147456, 128, 128);
    wtr(pf_w0, wtP0, 128, 128);
    wtr(pf_w1, wtP1, 128, 128);
    wtr(pf_w2, wtP2, 64, 128);

    k_buildx0<<<dim3((4 * 16 * HW2 + 255) / 256), 256, 0, stream>>>(features, gf, A);

    auto grid8 = [](int OH, int OW, int N) {
        return dim3((OW + 7) / 8, (OH + 7) / 8, N);
    };

    // embedding ladder
    k_convd<16, 128><<<grid8(114, 114, 4), 256, 0, stream>>>(A, wt0, emb_b0, B, 116, 116, 1, 0);
    k_convd<128,128><<<grid8(112, 112, 4), 256, 0, stream>>>(B, wtE0 + 0*147456, emb_b + 0*128, A, 114, 114, 1, 0);
    k_convd<128,128><<<grid8(110, 110, 4), 256, 0, stream>>>(A, wtE0 + 1*147456, emb_b + 1*128, B, 112, 112, 1, 0);
    k_convd<128,128><<<grid8(108, 108, 4), 256, 0, stream>>>(B, wtE0 + 2*147456, emb_b + 2*128, A, 110, 110, 1, 0);
    k_convd<128,128><<<grid8(106, 106, 4), 256, 0, stream>>>(A, wtE0 + 3*147456, emb_b + 3*128, B, 108, 108, 1, 0);
    k_convd<128,128><<<grid8(104, 104, 4), 256, 0, stream>>>(B, wtE0 + 4*147456, emb_b + 4*128, A, 106, 106, 1, 0);
    k_convd<128,128><<<grid8(102, 102, 4), 256, 0, stream>>>(A, wtE0 + 5*147456, emb_b + 5*128, B, 104, 104, 0, 0);

    // max over spp: B (4,128,102,102) -> A (128,102,102)
    k_sppmax<<<dim3(1331712 / 256), 256, 0, stream>>>(B, A);

    // pixel-feature convs (N=1); last one stores transposed (9216,64)
    k_convd<128,128><<<grid8(100, 100, 1), 256, 0, stream>>>(A, wtP0, pf_b0, B, 102, 102, 1, 0);
    k_convd<128,128><<<grid8(98,  98,  1), 256, 0, stream>>>(B, wtP1, pf_b1, A, 100, 100, 1, 0);
    k_convd<128, 64><<<grid8(96,  96,  1), 256, 0, stream>>>(A, wtP2, pf_b2, B, 98,  98,  0, 1);

    // fused MLP: pfeat_t in B -> wts in A (921600 floats)
    k_mlp<<<dim3(7200), 128, 0, stream>>>(features, B, sf_w, sf_b,
                                          kp_w0, kp_b0, kp_w1, kp_b1, kp_w2, kp_b2, A);

    // weighted radiance -> out
    k_reduce<<<dim3(36), 256, 0, stream>>>(A, radiance, out);
}

// Round 8
// 2643.317 us; speedup vs baseline: 1.5782x; 1.0990x over previous
//
#include <hip/hip_runtime.h>

// PASSING numerics contract (round 5, absmax 0.00195): every conv output must
// be a strictly sequential fp32 FMA chain in (ky,kx outer, cin inner) order,
// bias added after, fp32 stores. MLP layers: per-output sequential ascending-i
// chain, +bias, lrelu. Do NOT reorder/split K, do NOT change dtype.
//
// Round 8: MLP tile-GEMM. Block=256 taps; vx[k][tap] in LDS (64 KB); wave owns
// 16 outs (uniform -> contiguous s_load_dwordx16 of transposed w[k][o]); lane
// owns 4 taps (ds_read_b128). 64 FMA per 16 weight words: 4x less scalar
// traffic than round 7 (which stalled at VALUBusy 46% on s_load latency).

#define HW2 13456   // 116*116
#define NF  12
#define NGF 4

__device__ __forceinline__ float lrelu_f(float x) { return x > 0.f ? x : 0.01f * x; }

// ---------------- build x0: (4,16,116,116) = concat(gf bcast, features) ------------
__global__ __launch_bounds__(256) void k_buildx0(const float* __restrict__ features,
                                                 const float* __restrict__ gf,
                                                 float* __restrict__ out) {
    int i = blockIdx.x * 256 + threadIdx.x;
    const int total = 4 * 16 * HW2;
    if (i >= total) return;
    int n  = i / (16 * HW2);
    int r  = i - n * (16 * HW2);
    int c  = r / HW2;
    int yx = r - c * HW2;
    float v = (c < NGF) ? gf[c] : features[(n * NF + (c - NGF)) * HW2 + yx];
    out[i] = v;
}

// ---------------- weight transpose: W[m][cin][ky][kx] -> Wt[kyx][cin][m] -----------
__global__ __launch_bounds__(256) void k_wt(const float* __restrict__ w,
                                            float* __restrict__ wt,
                                            int Cout, int Cin) {
    int i = blockIdx.x * 256 + threadIdx.x;
    int total = Cout * Cin * 9;
    if (i >= total) return;
    int m   = i / (Cin * 9);
    int r   = i - m * (Cin * 9);
    int cin = r / 9;
    int kyx = r - cin * 9;
    wt[(kyx * Cin + cin) * Cout + m] = w[i];
}

// ---------------- small transpose for kp weights: (64,64) -> [k][o] ----------------
__global__ __launch_bounds__(256) void k_wt2(const float* __restrict__ w,
                                             float* __restrict__ wt) {
    int i = blockIdx.x * 256 + threadIdx.x;  // 4096
    if (i >= 4096) return;
    int o = i >> 6, k = i & 63;
    wt[k * 64 + o] = w[i];
}

// ---------------- direct 3x3 VALID conv, order-preserving ----------------
template <int CIN, int COUT>
__global__ __launch_bounds__(256) void k_convd(const float* __restrict__ in,
                                               const float* __restrict__ wt,
                                               const float* __restrict__ bias,
                                               float* __restrict__ out,
                                               int H, int W, int relu, int tout) {
    constexpr int MW = COUT / 4;
    const int OH = H - 2, OW = W - 2;
    const int n   = blockIdx.z;
    const int ty0 = blockIdx.y * 8, tx0 = blockIdx.x * 8;

    __shared__ float It[CIN * 100];   // [cin][y(10)][x(10)]

    const int tid = threadIdx.x;

    const float* inb = in + (size_t)n * CIN * H * W;
    for (int i = tid; i < CIN * 100; i += 256) {
        int cin = i / 100;
        int r   = i - cin * 100;
        int y   = r / 10;
        int x   = r - y * 10;
        int gy = ty0 + y; if (gy > H - 1) gy = H - 1;
        int gx = tx0 + x; if (gx > W - 1) gx = W - 1;
        It[i] = inb[((size_t)cin * H + gy) * W + gx];
    }
    __syncthreads();

    const int lane  = tid & 63;
    const int wv    = __builtin_amdgcn_readfirstlane(tid >> 6);
    const int ly    = lane >> 3, lx = lane & 7;
    const int lbase = ly * 10 + lx;

    float acc[MW];
    #pragma unroll
    for (int mi = 0; mi < MW; ++mi) acc[mi] = 0.f;

    for (int ky = 0; ky < 3; ++ky) {
        for (int kx = 0; kx < 3; ++kx) {
            const int kyx  = ky * 3 + kx;
            const int aoff = lbase + ky * 10 + kx;
            const float* wrow = wt + (size_t)kyx * CIN * COUT + wv * MW;  // uniform
            #pragma unroll 8
            for (int cin = 0; cin < CIN; ++cin) {
                float v = It[cin * 100 + aoff];
                const float* wr = wrow + (size_t)cin * COUT;   // uniform -> s_load
                #pragma unroll
                for (int mi = 0; mi < MW; ++mi)
                    acc[mi] += wr[mi] * v;
            }
        }
    }

    int oy = ty0 + ly, ox = tx0 + lx;
    if (oy < OH && ox < OW) {
        if (tout) {
            float* ob = out + (size_t)(oy * OW + ox) * COUT;
            #pragma unroll
            for (int mi = 0; mi < MW; ++mi) {
                int m = wv * MW + mi;
                float val = acc[mi] + bias[m];
                if (relu) val = lrelu_f(val);
                ob[m] = val;
            }
        } else {
            #pragma unroll
            for (int mi = 0; mi < MW; ++mi) {
                int m = wv * MW + mi;
                float val = acc[mi] + bias[m];
                if (relu) val = lrelu_f(val);
                out[(((size_t)n * COUT + m) * OH + oy) * OW + ox] = val;
            }
        }
    }
}

// ---------------- max over spp: (4,128,102,102) -> (128,102,102) ----------------
__global__ __launch_bounds__(256) void k_sppmax(const float* __restrict__ in,
                                                float* __restrict__ out) {
    int i = blockIdx.x * 256 + threadIdx.x;
    const int total = 128 * 102 * 102;  // 1331712
    if (i >= total) return;
    float m = in[i];
    #pragma unroll
    for (int s = 1; s < 4; ++s) m = fmaxf(m, in[i + s * total]);
    out[i] = m;
}

// ---------------- fused per-tap MLP -> wts (921600), tile-GEMM layers ----------
// Block = 256 threads = 256 taps. vx[k][tap] LDS (64 KB). Layers kp0/kp1:
// wave -> 16 outs (uniform weights, contiguous s_load from w[k][o] transposed),
// lane -> 4 taps (ds_read_b128). Each output: single ascending-k fp32 chain.
__global__ __launch_bounds__(256) void k_mlp(const float* __restrict__ features,
                                             const float* __restrict__ pfeat_t,  // (9216,64)
                                             const float* __restrict__ sf_w,     // (64,12)
                                             const float* __restrict__ sf_b,
                                             const float* __restrict__ w0t,      // [k][o]
                                             const float* __restrict__ b0,
                                             const float* __restrict__ w1t,      // [k][o]
                                             const float* __restrict__ b1,
                                             const float* __restrict__ w2, const float* __restrict__ b2,
                                             float* __restrict__ wts) {
    __shared__ float vx[64][256];  // [k][tap]  64 KB
    const int t   = threadIdx.x;
    const int gid = blockIdx.x * 256 + t;  // 3600*256 = 921600 exactly
    {
        int p  = gid / 100;
        int r  = gid - p * 100;
        int s  = r / 25;
        int tp = r - s * 25;
        int dy = tp / 5;
        int dx = tp - dy * 5;
        int h  = p / 96;
        int w  = p - h * 96;

        // gather 12 tap features (crop offset 8)
        int y = 8 + h + dy, x = 8 + w + dx;
        const float* fb = features + (size_t)(s * NF) * HW2 + (size_t)y * 116 + x;
        float f[12];
        #pragma unroll
        for (int i = 0; i < 12; ++i) f[i] = fb[i * HW2];
        f[0] += (float)(dx - 2);
        f[1] += (float)(dy - 2);

        // sf = taps.sf_w + sf_b ; then v = pairf + sf  (reference order)
        const float* pft = pfeat_t + (size_t)p * 64;
        #pragma unroll
        for (int o = 0; o < 64; ++o) {
            float a = 0.f;
            #pragma unroll
            for (int i = 0; i < 12; ++i) a += sf_w[o * 12 + i] * f[i];
            a += sf_b[o];
            vx[o][t] = pft[o] + a;
        }
    }
    __syncthreads();

    const int lane = t & 63;
    const int og   = 16 * __builtin_amdgcn_readfirstlane(t >> 6);  // wave's out base
    const int tl   = lane * 4;                                      // lane's tap base

    // ---- kp0: acc[16 outs][4 taps], k ascending ----
    {
        float acc[16][4];
        #pragma unroll
        for (int j = 0; j < 16; ++j)
            #pragma unroll
            for (int c = 0; c < 4; ++c) acc[j][c] = 0.f;
        #pragma unroll 4
        for (int k = 0; k < 64; ++k) {
            float4 xv = *(const float4*)(&vx[k][tl]);
            const float* wr = w0t + k * 64 + og;   // uniform, contiguous 16 words
            #pragma unroll
            for (int j = 0; j < 16; ++j) {
                float wj = wr[j];
                acc[j][0] += wj * xv.x; acc[j][1] += wj * xv.y;
                acc[j][2] += wj * xv.z; acc[j][3] += wj * xv.w;
            }
        }
        __syncthreads();   // all reads of vx done
        #pragma unroll
        for (int j = 0; j < 16; ++j) {
            float bj = b0[og + j];
            float4 ov;
            ov.x = lrelu_f(acc[j][0] + bj); ov.y = lrelu_f(acc[j][1] + bj);
            ov.z = lrelu_f(acc[j][2] + bj); ov.w = lrelu_f(acc[j][3] + bj);
            *(float4*)(&vx[og + j][tl]) = ov;
        }
        __syncthreads();
    }

    // ---- kp1 ----
    {
        float acc[16][4];
        #pragma unroll
        for (int j = 0; j < 16; ++j)
            #pragma unroll
            for (int c = 0; c < 4; ++c) acc[j][c] = 0.f;
        #pragma unroll 4
        for (int k = 0; k < 64; ++k) {
            float4 xv = *(const float4*)(&vx[k][tl]);
            const float* wr = w1t + k * 64 + og;
            #pragma unroll
            for (int j = 0; j < 16; ++j) {
                float wj = wr[j];
                acc[j][0] += wj * xv.x; acc[j][1] += wj * xv.y;
                acc[j][2] += wj * xv.z; acc[j][3] += wj * xv.w;
            }
        }
        __syncthreads();
        #pragma unroll
        for (int j = 0; j < 16; ++j) {
            float bj = b1[og + j];
            float4 ov;
            ov.x = lrelu_f(acc[j][0] + bj); ov.y = lrelu_f(acc[j][1] + bj);
            ov.z = lrelu_f(acc[j][2] + bj); ov.w = lrelu_f(acc[j][3] + bj);
            *(float4*)(&vx[og + j][tl]) = ov;
        }
        __syncthreads();
    }

    // ---- kp2: per-tap dot, ascending i ----
    {
        float a = 0.f;
        #pragma unroll
        for (int i = 0; i < 64; ++i) a += w2[i] * vx[i][t];
        a += b2[0];
        wts[gid] = a;
    }
}

// ---------------- final weighted-radiance reduction -> out (3,96,96), fp32 --------
__global__ __launch_bounds__(256) void k_reduce(const float* __restrict__ wts,
                                                const float* __restrict__ radiance,
                                                float* __restrict__ out) {
    int p = blockIdx.x * 256 + threadIdx.x;  // 9216
    if (p >= 9216) return;
    int h = p / 96, w = p - h * 96;
    float sw = 0.f, un0 = 0.f, un1 = 0.f, un2 = 0.f;
    const float* wp = wts + (size_t)p * 100;
    for (int s = 0; s < 4; ++s) {
        #pragma unroll
        for (int dy = 0; dy < 5; ++dy) {
            #pragma unroll
            for (int dx = 0; dx < 5; ++dx) {
                float wv = wp[s * 25 + dy * 5 + dx];
                sw += wv;
                int y = 8 + h + dy, x = 8 + w + dx;
                const float* rb = radiance + (size_t)(s * 3) * HW2 + (size_t)y * 116 + x;
                un0 += wv * rb[0 * HW2];
                un1 += wv * rb[1 * HW2];
                un2 += wv * rb[2 * HW2];
            }
        }
    }
    float inv = 1.f / (sw + 1e-8f);
    out[0 * 9216 + p] = un0 * inv;
    out[1 * 9216 + p] = un1 * inv;
    out[2 * 9216 + p] = un2 * inv;
}

extern "C" void kernel_launch(void* const* d_in, const int* in_sizes, int n_in,
                              void* d_out, int out_size, void* d_ws, size_t ws_size,
                              hipStream_t stream) {
    const float* features = (const float*)d_in[0];
    const float* radiance = (const float*)d_in[1];
    const float* gf       = (const float*)d_in[2];
    const float* emb_w0   = (const float*)d_in[3];
    const float* emb_b0   = (const float*)d_in[4];
    const float* emb_w    = (const float*)d_in[5];
    const float* emb_b    = (const float*)d_in[6];
    const float* pf_w0    = (const float*)d_in[7];
    const float* pf_b0    = (const float*)d_in[8];
    const float* pf_w1    = (const float*)d_in[9];
    const float* pf_b1    = (const float*)d_in[10];
    const float* pf_w2    = (const float*)d_in[11];
    const float* pf_b2    = (const float*)d_in[12];
    const float* sf_w     = (const float*)d_in[13];
    const float* sf_b     = (const float*)d_in[14];
    const float* kp_w0    = (const float*)d_in[15];
    const float* kp_b0    = (const float*)d_in[16];
    const float* kp_w1    = (const float*)d_in[17];
    const float* kp_b1    = (const float*)d_in[18];
    const float* kp_w2    = (const float*)d_in[19];
    const float* kp_b2    = (const float*)d_in[20];
    float* out = (float*)d_out;

    // ---- workspace layout ----
    float* WT = (float*)d_ws;
    float* wt0  = WT;                      // conv1: 16x9x128      = 18432
    float* wtE0 = WT + 18432;              // emb i: 128x9x128     = 147456 each
    float* wtP0 = WT + 18432 + 6 * 147456; // 903168
    float* wtP1 = WT + 1050624;
    float* wtP2 = WT + 1198080;            // 64-out: 128x9x64 = 73728 (end 1271808)
    float* w0t  = WT + 1271808;            // kp0 transposed [k][o] = 4096
    float* w1t  = WT + 1275904;            // kp1 transposed        = 4096 (end 1280000)
    float* A = WT + 1280000;               // ping-pong fp32 buffers, 6653952 floats each
    float* B = A + 6653952;

    // ---- weight transposes (tiny) ----
    auto wtr = [&](const float* w, float* dst, int Cout, int Cin) {
        int total = Cout * Cin * 9;
        k_wt<<<dim3((total + 255) / 256), 256, 0, stream>>>(w, dst, Cout, Cin);
    };
    wtr(emb_w0, wt0, 128, 16);
    for (int i = 0; i < 6; ++i) wtr(emb_w + i * 147456, wtE0 + i * 147456, 128, 128);
    wtr(pf_w0, wtP0, 128, 128);
    wtr(pf_w1, wtP1, 128, 128);
    wtr(pf_w2, wtP2, 64, 128);
    k_wt2<<<dim3(16), 256, 0, stream>>>(kp_w0, w0t);
    k_wt2<<<dim3(16), 256, 0, stream>>>(kp_w1, w1t);

    k_buildx0<<<dim3((4 * 16 * HW2 + 255) / 256), 256, 0, stream>>>(features, gf, A);

    auto grid8 = [](int OH, int OW, int N) {
        return dim3((OW + 7) / 8, (OH + 7) / 8, N);
    };

    // embedding ladder
    k_convd<16, 128><<<grid8(114, 114, 4), 256, 0, stream>>>(A, wt0, emb_b0, B, 116, 116, 1, 0);
    k_convd<128,128><<<grid8(112, 112, 4), 256, 0, stream>>>(B, wtE0 + 0*147456, emb_b + 0*128, A, 114, 114, 1, 0);
    k_convd<128,128><<<grid8(110, 110, 4), 256, 0, stream>>>(A, wtE0 + 1*147456, emb_b + 1*128, B, 112, 112, 1, 0);
    k_convd<128,128><<<grid8(108, 108, 4), 256, 0, stream>>>(B, wtE0 + 2*147456, emb_b + 2*128, A, 110, 110, 1, 0);
    k_convd<128,128><<<grid8(106, 106, 4), 256, 0, stream>>>(A, wtE0 + 3*147456, emb_b + 3*128, B, 108, 108, 1, 0);
    k_convd<128,128><<<grid8(104, 104, 4), 256, 0, stream>>>(B, wtE0 + 4*147456, emb_b + 4*128, A, 106, 106, 1, 0);
    k_convd<128,128><<<grid8(102, 102, 4), 256, 0, stream>>>(A, wtE0 + 5*147456, emb_b + 5*128, B, 104, 104, 0, 0);

    // max over spp: B (4,128,102,102) -> A (128,102,102)
    k_sppmax<<<dim3(1331712 / 256), 256, 0, stream>>>(B, A);

    // pixel-feature convs (N=1); last one stores transposed (9216,64)
    k_convd<128,128><<<grid8(100, 100, 1), 256, 0, stream>>>(A, wtP0, pf_b0, B, 102, 102, 1, 0);
    k_convd<128,128><<<grid8(98,  98,  1), 256, 0, stream>>>(B, wtP1, pf_b1, A, 100, 100, 1, 0);
    k_convd<128, 64><<<grid8(96,  96,  1), 256, 0, stream>>>(A, wtP2, pf_b2, B, 98,  98,  0, 1);

    // fused MLP: pfeat_t in B -> wts in A (921600 floats)
    k_mlp<<<dim3(3600), 256, 0, stream>>>(features, B, sf_w, sf_b,
                                          w0t, kp_b0, w1t, kp_b1, kp_w2, kp_b2, A);

    // weighted radiance -> out
    k_reduce<<<dim3(36), 256, 0, stream>>>(A, radiance, out);
}